// Round 11
// baseline (938.952 us; speedup 1.0000x reference)
//
#include <hip/hip_runtime.h>

typedef _Float16 half8_t __attribute__((ext_vector_type(8)));
typedef _Float16 half4_t __attribute__((ext_vector_type(4)));
typedef float f32x4 __attribute__((ext_vector_type(4)));

#define MFMA16(a, b, c) __builtin_amdgcn_mfma_f32_16x16x32_f16((a), (b), (c), 0, 0, 0)

typedef const unsigned int __attribute__((address_space(1)))* gas_ptr;
typedef unsigned int __attribute__((address_space(3)))* las_ptr;

__device__ __forceinline__ void gload16(const void* g, void* l) {
    __builtin_amdgcn_global_load_lds((gas_ptr)g, (las_ptr)l, 16, 0, 0);
}

// m204 bijective XCD swizzle: contiguous wgid chunk per XCD
__device__ __forceinline__ int xcd_swizzle(int bid, int nwg) {
    int xcd = bid & 7, i = bid >> 3;
    int q = nwg >> 3, r = nwg & 7;
    return (xcd < r ? xcd * (q + 1) : r * (q + 1) + (xcd - r) * q) + i;
}

// ---------------- convert / transpose ----------------

__global__ void cvt_f2h_kernel(const float* __restrict__ in, _Float16* __restrict__ out, int n4) {
    int stride = gridDim.x * blockDim.x;
    for (int i = blockIdx.x * blockDim.x + threadIdx.x; i < n4; i += stride) {
        f32x4 v = *(const f32x4*)(in + (size_t)4 * i);
        half4_t h;
        h[0] = (_Float16)v[0]; h[1] = (_Float16)v[1];
        h[2] = (_Float16)v[2]; h[3] = (_Float16)v[3];
        *(half4_t*)(out + (size_t)4 * i) = h;
    }
}

// out[j][k] = in[k][j], K fixed at 768
__global__ void transpose768_kernel(const float* __restrict__ in, _Float16* __restrict__ out, int ncols) {
    int idx = blockIdx.x * 256 + threadIdx.x;
    int total = ncols * 768;
    if (idx < total) {
        int j = idx / 768;
        int k = idx - j * 768;
        out[idx] = (_Float16)in[(size_t)k * ncols + j];
    }
}

// ---------------- GEMM core: 128x256 tile (kept for gemm_proj, R9-validated) ----------

#define STG(buf, kof)                                                             \
    {                                                                             \
        _Float16* Ad = lds + (buf) * 12288 + wave * 512;                          \
        _Float16* Bd = lds + (buf) * 12288 + 4096 + wave * 512;                   \
        gload16(Arow + (kof), Ad);                                                \
        gload16(Brow + (kof), Bd);                                                \
        gload16(Brow + (kof) + 98304, Bd + 4096);                                 \
    }

__device__ __forceinline__ void run_gemm128x256(const _Float16* __restrict__ A,
                                                const _Float16* __restrict__ Bt,
                                                int mbase, int nbase,
                                                _Float16* lds,          // 24576 f16
                                                f32x4 (&acc)[4][4]) {
    const int tid = threadIdx.x;
    const int lane = tid & 63;
    const int wave = tid >> 6;
    const int wr = wave >> 2;
    const int wc = wave & 3;
    const int l15 = lane & 15;
    const int l4 = lane >> 4;
    const int rsw = ((l4 ^ ((l15 >> 1) & 3)) << 3);
    const int ksw = (((tid & 3) ^ ((tid >> 3) & 3)) << 3);

    #pragma unroll
    for (int mi = 0; mi < 4; ++mi)
        #pragma unroll
        for (int ni = 0; ni < 4; ++ni)
            acc[mi][ni] = (f32x4){0.f, 0.f, 0.f, 0.f};

    const _Float16* Arow = A + (size_t)(mbase + (tid >> 2)) * 768 + ksw;
    const _Float16* Brow = Bt + (size_t)(nbase + (tid >> 2)) * 768 + ksw;

    STG(0, 0)
    __syncthreads();

    #pragma unroll 2
    for (int kt = 0; kt < 24; ++kt) {
        const int buf = kt & 1;
        if (kt < 23) STG(buf ^ 1, (kt + 1) * 32)

        const _Float16* Ac = lds + buf * 12288;
        const _Float16* Bc = Ac + 4096;
        half8_t a[4], b[4];
        #pragma unroll
        for (int mi = 0; mi < 4; ++mi)
            a[mi] = *(const half8_t*)(Ac + (wr * 64 + mi * 16 + l15) * 32 + rsw);
        #pragma unroll
        for (int ni = 0; ni < 4; ++ni)
            b[ni] = *(const half8_t*)(Bc + (wc * 64 + ni * 16 + l15) * 32 + rsw);
        #pragma unroll
        for (int mi = 0; mi < 4; ++mi)
            #pragma unroll
            for (int ni = 0; ni < 4; ++ni)
                acc[mi][ni] = MFMA16(a[mi], b[ni], acc[mi][ni]);
        __syncthreads();
    }
}

// GEMM2: out = fused @ w_proj + b_proj (f32 out)
__global__ __launch_bounds__(512, 4) void gemm_proj_kernel(
    const _Float16* __restrict__ fused, const _Float16* __restrict__ wprojT,
    const float* __restrict__ b_proj, float* __restrict__ out) {
    __shared__ _Float16 lds[24576];
    int wgid = xcd_swizzle(blockIdx.x, 392 * 3);
    int mtile = wgid / 3, ntile = wgid - mtile * 3;
    f32x4 acc[4][4];
    run_gemm128x256(fused, wprojT, mtile * 128, ntile * 256, lds, acc);

    const int tid = threadIdx.x;
    const int lane = tid & 63;
    const int wave = tid >> 6;
    const int wr = wave >> 2;
    const int wc = wave & 3;
    const int l15 = lane & 15;
    const int l4 = lane >> 4;

    #pragma unroll
    for (int mi = 0; mi < 4; ++mi) {
        #pragma unroll
        for (int ni = 0; ni < 4; ++ni) {
            int gc = ntile * 256 + wc * 64 + ni * 16 + l15;
            float bp = b_proj[gc];
            #pragma unroll
            for (int r = 0; r < 4; ++r) {
                int gr = mtile * 128 + wr * 64 + mi * 16 + l4 * 4 + r;
                out[(size_t)gr * 768 + gc] = acc[mi][ni][r] + bp;
            }
        }
    }
}

// ---------------- FUSED qkv-GEMM + attention: one block per (b, h) ----------------
// GEMM: qkv_h[224pad x 192] = x_b[224 x 768] @ w_slice_h; epilogue -> LDS
// (q_l natural [224][72], k_t/v_t transposed [64][232], +pos_enc/relu in-reg);
// then kv = k^T v, ksum, z, PV + dwconv, write fused. No qkv HBM round-trip.
// LDS map (f16 units): stg 0..26624 (2 x 13312: x[224][32]=7168 + w[192][32]=6144)
//   q_l 26624 (+16128)  k_t 42752 (+14848)  v_t 57600 (+14848)  kv_l 72448 (+4096)
__global__ __launch_bounds__(512) void fused_qkv_attn_kernel(
    const _Float16* __restrict__ xh, const _Float16* __restrict__ wqkvT,
    const float* __restrict__ pos_enc,
    const float* __restrict__ dwc_w, const float* __restrict__ dwc_b,
    _Float16* __restrict__ fused) {
    __shared__ _Float16 smem[76544];
    __shared__ float ksum_p[512];
    __shared__ float ksum[64];
    __shared__ float zz[196];

    const int bh = xcd_swizzle(blockIdx.x, 3072);
    const int b = bh / 12, h = bh - b * 12;
    const int tid = threadIdx.x;
    const int lane = tid & 63;
    const int wave = tid >> 6;
    const int wr = wave >> 2;        // 0..1 (M half, 112 rows)
    const int wc = wave & 3;         // 0..3 (N quarter, 48 cols)
    const int l15 = lane & 15;
    const int l4 = lane >> 4;
    const int rsw = ((l4 ^ ((l15 >> 1) & 3)) << 3);          // frag-read k-slot swizzle
    const int ssw = (((lane & 3) ^ ((lane >> 3) & 3)) << 3); // staging source pre-swizzle
    _Float16* q_l = smem + 26624;
    _Float16* k_t = smem + 42752;
    _Float16* v_t = smem + 57600;
    _Float16* kv_l = smem + 72448;

    // zero pads: k_t/v_t cols [196,232) (u32 x 18 per row), q_l rows [196,224)
    for (int idx = tid; idx < 1152; idx += 512) {
        int c = idx / 18, u = idx - c * 18;
        ((unsigned int*)(k_t + c * 232 + 196))[u] = 0u;
        ((unsigned int*)(v_t + c * 232 + 196))[u] = 0u;
    }
    for (int i = tid; i < 1008; i += 512) ((unsigned int*)(q_l + 196 * 72))[i] = 0u;

    // ---- GEMM phase: acc[7][3], BK=32, 24 K-iters, dbuf ----
    f32x4 acc[7][3];
    #pragma unroll
    for (int mi = 0; mi < 7; ++mi)
        #pragma unroll
        for (int ni = 0; ni < 3; ++ni)
            acc[mi][ni] = (f32x4){0.f, 0.f, 0.f, 0.f};

    const size_t xbase = (size_t)b * 196;
    const int rl16 = lane >> 2;   // row within 16-row chunk

    // stage K-tile (26 wave-instrs: 14 x-chunks + 12 w-chunks), wave w does c = w+8i
    #define STAGEF(buf, kof)                                                          \
        {                                                                             \
            _Pragma("unroll")                                                         \
            for (int i = 0; i < 4; ++i) {                                             \
                int c = wave + 8 * i;                                                 \
                if (c < 26) {                                                         \
                    _Float16* dst = smem + (buf) * 13312 + c * 512;                   \
                    if (c < 14) {                                                     \
                        gload16(xh + (xbase + 16 * c + rl16) * 768 + (kof) + ssw, dst); \
                    } else {                                                          \
                        int j = 16 * (c - 14) + rl16;                                 \
                        int wrow = (j >> 6) * 768 + h * 64 + (j & 63);                \
                        gload16(wqkvT + (size_t)wrow * 768 + (kof) + ssw, dst);       \
                    }                                                                 \
                }                                                                     \
            }                                                                         \
        }

    STAGEF(0, 0)
    __syncthreads();

    #pragma unroll 2
    for (int kt = 0; kt < 24; ++kt) {
        const int buf = kt & 1;
        if (kt < 23) STAGEF(buf ^ 1, (kt + 1) * 32)

        const _Float16* xs = smem + buf * 13312;
        const _Float16* ws_ = xs + 7168;
        half8_t a[7], bfr[3];
        #pragma unroll
        for (int mi = 0; mi < 7; ++mi)
            a[mi] = *(const half8_t*)(xs + (wr * 112 + mi * 16 + l15) * 32 + rsw);
        #pragma unroll
        for (int ni = 0; ni < 3; ++ni)
            bfr[ni] = *(const half8_t*)(ws_ + (wc * 48 + ni * 16 + l15) * 32 + rsw);
        #pragma unroll
        for (int mi = 0; mi < 7; ++mi)
            #pragma unroll
            for (int ni = 0; ni < 3; ++ni)
                acc[mi][ni] = MFMA16(a[mi], bfr[ni], acc[mi][ni]);
        __syncthreads();
    }

    // ---- epilogue: acc -> q_l / k_t / v_t (pos_enc + relu in-reg) ----
    #pragma unroll
    for (int mi = 0; mi < 7; ++mi) {
        int n0 = wr * 112 + mi * 16 + l4 * 4;
        #pragma unroll
        for (int ni = 0; ni < 3; ++ni) {
            int c = wc * 48 + ni * 16 + l15;     // 0..191
            int seg = c >> 6, d = c & 63;
            if (seg == 0) {
                #pragma unroll
                for (int r = 0; r < 4; ++r) {
                    int n = n0 + r;
                    if (n < 196) q_l[n * 72 + d] = (_Float16)fmaxf(acc[mi][ni][r], 0.f);
                }
            } else if (n0 < 196) {
                half4_t w;
                #pragma unroll
                for (int r = 0; r < 4; ++r) {
                    float v = acc[mi][ni][r];
                    if (seg == 1) { v += pos_enc[(n0 + r) * 768 + h * 64 + d]; v = fmaxf(v, 0.f); }
                    w[r] = (_Float16)v;
                }
                *(half4_t*)(((seg == 1) ? k_t : v_t) + d * 232 + n0) = w;
            }
        }
    }
    __syncthreads();

    // ---- kv = k^T v (64x64): wave -> (ct, dt0),(ct,dt0+1); store kv_l swizzled ----
    {
        int ct = wave >> 1, dt0 = (wave & 1) * 2;
        f32x4 acc0 = {0.f, 0.f, 0.f, 0.f}, acc1 = {0.f, 0.f, 0.f, 0.f};
        #pragma unroll
        for (int ks = 0; ks < 7; ++ks) {
            half8_t a  = *(const half8_t*)(k_t + (ct * 16 + l15) * 232 + ks * 32 + l4 * 8);
            half8_t b0 = *(const half8_t*)(v_t + (dt0 * 16 + l15) * 232 + ks * 32 + l4 * 8);
            half8_t b1 = *(const half8_t*)(v_t + (dt0 * 16 + 16 + l15) * 232 + ks * 32 + l4 * 8);
            acc0 = MFMA16(a, b0, acc0);
            acc1 = MFMA16(a, b1, acc1);
        }
        half4_t h0, h1;
        #pragma unroll
        for (int r = 0; r < 4; ++r) { h0[r] = (_Float16)acc0[r]; h1[r] = (_Float16)acc1[r]; }
        int slot = ct * 2 + (l4 >> 1), sub = (l4 & 1) * 4;
        int d0 = dt0 * 16 + l15, d1 = d0 + 16;
        *(half4_t*)(kv_l + d0 * 64 + (((slot ^ (d0 & 7)) << 3) + sub)) = h0;
        *(half4_t*)(kv_l + d1 * 64 + (((slot ^ (d1 & 7)) << 3) + sub)) = h1;
    }
    // ksum partials
    {
        int n0 = wave * 25;
        int n1 = (n0 + 25 < 196) ? (n0 + 25) : 196;
        float s = 0.f;
        for (int n = n0; n < n1; ++n) s += (float)k_t[lane * 232 + n];
        ksum_p[wave * 64 + lane] = s;
    }
    __syncthreads();
    if (tid < 64) {
        float s = 0.f;
        #pragma unroll
        for (int w = 0; w < 8; ++w) s += ksum_p[w * 64 + tid];
        ksum[tid] = s;
    }
    __syncthreads();
    if (tid < 196) {
        float s = 0.f;
        #pragma unroll
        for (int c8 = 0; c8 < 8; ++c8) {
            half8_t qv = *(const half8_t*)(q_l + tid * 72 + c8 * 8);
            #pragma unroll
            for (int j = 0; j < 8; ++j) s += (float)qv[j] * ksum[c8 * 8 + j];
        }
        zz[tid] = 1.0f / (s + 1e-6f);
    }
    __syncthreads();

    // ---- PV + depthwise conv ----
    for (int t = wave; t < 52; t += 8) {
        int mt = t >> 2, dt = t & 3;
        int d = dt * 16 + l15;
        f32x4 pacc = {0.f, 0.f, 0.f, 0.f};
        half8_t a0 = *(const half8_t*)(q_l + (mt * 16 + l15) * 72 + l4 * 8);
        half8_t a1 = *(const half8_t*)(q_l + (mt * 16 + l15) * 72 + 32 + l4 * 8);
        half8_t b0 = *(const half8_t*)(kv_l + d * 64 + ((l4 ^ (d & 7)) << 3));
        half8_t b1 = *(const half8_t*)(kv_l + d * 64 + (((l4 + 4) ^ (d & 7)) << 3));
        pacc = MFMA16(a0, b0, pacc);
        pacc = MFMA16(a1, b1, pacc);

        float bd = dwc_b[d];
        float wcf[25];
        #pragma unroll
        for (int j2 = 0; j2 < 25; ++j2) wcf[j2] = dwc_w[d * 25 + j2];

        #pragma unroll
        for (int r = 0; r < 4; ++r) {
            int i = mt * 16 + l4 * 4 + r;
            if (i < 196) {
                int y = i / 14, x2 = i - y * 14;
                float cacc = bd;
                #pragma unroll
                for (int ky = 0; ky < 5; ++ky) {
                    int yy = y + ky - 2;
                    bool oky = (unsigned)yy < 14u;
                    #pragma unroll
                    for (int kx = 0; kx < 5; ++kx) {
                        int xx = x2 + kx - 2;
                        if (oky && (unsigned)xx < 14u)
                            cacc += (float)v_t[d * 232 + (yy * 14 + xx)] * wcf[ky * 5 + kx];
                    }
                }
                float res = pacc[r] * zz[i] + cacc;
                fused[((size_t)b * 196 + i) * 768 + h * 64 + d] = (_Float16)res;
            }
        }
    }
}

// ---------------- launcher ----------------

extern "C" void kernel_launch(void* const* d_in, const int* in_sizes, int n_in,
                              void* d_out, int out_size, void* d_ws, size_t ws_size,
                              hipStream_t stream) {
    const float* x       = (const float*)d_in[0];
    const float* w_qkv   = (const float*)d_in[1];
    const float* pos_enc = (const float*)d_in[2];
    const float* dwc_w   = (const float*)d_in[3];
    const float* dwc_b   = (const float*)d_in[4];
    const float* w_proj  = (const float*)d_in[5];
    const float* b_proj  = (const float*)d_in[6];

    const size_t NEEDED = 340574208;
    if (ws_size < NEEDED) return;  // insufficient scratch; bail

    char* ws = (char*)d_ws;
    _Float16* xh     = (_Float16*)(ws + 0);          // 77,070,336 B  (x as f16; read-only here)
    _Float16* wqkvT  = (_Float16*)(ws + 77070336);   // 3,538,944
    _Float16* wprojT = (_Float16*)(ws + 80609280);   // 1,179,648
    _Float16* fused  = (_Float16*)(ws + 81788928);   // 77,070,336  (own buffer: fused kernel
                                                     //  reads xh while writing fused)

    cvt_f2h_kernel<<<4096, 256, 0, stream>>>(x, xh, 9633792);
    transpose768_kernel<<<(2304 * 768 + 255) / 256, 256, 0, stream>>>(w_qkv, wqkvT, 2304);
    transpose768_kernel<<<(768 * 768 + 255) / 256, 256, 0, stream>>>(w_proj, wprojT, 768);
    fused_qkv_attn_kernel<<<3072, 512, 0, stream>>>(xh, wqkvT, pos_enc, dwc_w, dwc_b, fused);
    gemm_proj_kernel<<<392 * 3, 512, 0, stream>>>(fused, wprojT, b_proj, (float*)d_out);
}

// Round 12
// 645.875 us; speedup vs baseline: 1.4538x; 1.4538x over previous
//
#include <hip/hip_runtime.h>

typedef _Float16 half8_t __attribute__((ext_vector_type(8)));
typedef _Float16 half4_t __attribute__((ext_vector_type(4)));
typedef float f32x4 __attribute__((ext_vector_type(4)));

#define MFMA16(a, b, c) __builtin_amdgcn_mfma_f32_16x16x32_f16((a), (b), (c), 0, 0, 0)

typedef const unsigned int __attribute__((address_space(1)))* gas_ptr;
typedef unsigned int __attribute__((address_space(3)))* las_ptr;

__device__ __forceinline__ void gload16(const void* g, void* l) {
    __builtin_amdgcn_global_load_lds((gas_ptr)g, (las_ptr)l, 16, 0, 0);
}

// m204 bijective XCD swizzle: contiguous wgid chunk per XCD
__device__ __forceinline__ int xcd_swizzle(int bid, int nwg) {
    int xcd = bid & 7, i = bid >> 3;
    int q = nwg >> 3, r = nwg & 7;
    return (xcd < r ? xcd * (q + 1) : r * (q + 1) + (xcd - r) * q) + i;
}

// ---------------- convert / transpose ----------------

__global__ void cvt_f2h_kernel(const float* __restrict__ in, _Float16* __restrict__ out, int n4) {
    int stride = gridDim.x * blockDim.x;
    for (int i = blockIdx.x * blockDim.x + threadIdx.x; i < n4; i += stride) {
        f32x4 v = *(const f32x4*)(in + (size_t)4 * i);
        half4_t h;
        h[0] = (_Float16)v[0]; h[1] = (_Float16)v[1];
        h[2] = (_Float16)v[2]; h[3] = (_Float16)v[3];
        *(half4_t*)(out + (size_t)4 * i) = h;
    }
}

// out[j][k] = in[k][j], K fixed at 768
__global__ void transpose768_kernel(const float* __restrict__ in, _Float16* __restrict__ out, int ncols) {
    int idx = blockIdx.x * 256 + threadIdx.x;
    int total = ncols * 768;
    if (idx < total) {
        int j = idx / 768;
        int k = idx - j * 768;
        out[idx] = (_Float16)in[(size_t)k * ncols + j];
    }
}

// ---------------- GEMM core: m97-class 128x128 tile, 4 waves, BK=64, single-buffer ----
// A: [M][768] f16 (K contiguous); Bt: [Nout][768] f16 (K contiguous)
// LDS: As [128][64] + Bs [128][64] f16 = 32 KiB single-buffered -> ~4 blocks/CU;
// co-resident blocks hide each other's barrier drains (m114 / m97 structure).
// Swizzle (rule #21 both-sides): position p = tid + 256*i covers (row=p>>3, slot=p&7);
// LDS[r][s] = G[r][s ^ (r&7)] via source slot (lane&7)^(lane>>3) (dest stays linear
// for gload_lds); frag read slot = (h*4 + l4) ^ (l15&7) -> 8 slots x 2 lanes = free.
// Loop (proven sync class): STAGE ; __syncthreads ; ds_read + 32 MFMA ; __syncthreads.

#define STG128(kof)                                                               \
    {                                                                             \
        _Pragma("unroll")                                                         \
        for (int i = 0; i < 4; ++i) {                                             \
            gload16(ArowS + (kof) + i * 24576, As + wave * 512 + i * 2048);       \
            gload16(BrowS + (kof) + i * 24576, Bs + wave * 512 + i * 2048);       \
        }                                                                         \
    }

__device__ __forceinline__ void run_gemm128(const _Float16* __restrict__ A,
                                            const _Float16* __restrict__ Bt,
                                            int mbase, int nbase,
                                            _Float16* As, _Float16* Bs,   // 8192 f16 each
                                            f32x4 (&acc)[4][4]) {
    const int tid = threadIdx.x;
    const int lane = tid & 63;
    const int wave = tid >> 6;
    const int wm = (wave >> 1) * 64;
    const int wn = (wave & 1) * 64;
    const int l15 = lane & 15;
    const int l4 = lane >> 4;
    const int rs = l15 & 7;                                   // read swizzle key
    const int srow = lane >> 3;                               // staging row-in-8 (0..7)
    const int ssl = ((lane & 7) ^ srow) << 3;                 // staging source slot offset

    #pragma unroll
    for (int mi = 0; mi < 4; ++mi)
        #pragma unroll
        for (int ni = 0; ni < 4; ++ni)
            acc[mi][ni] = (f32x4){0.f, 0.f, 0.f, 0.f};

    const _Float16* ArowS = A + (size_t)(mbase + wave * 8 + srow) * 768 + ssl;
    const _Float16* BrowS = Bt + (size_t)(nbase + wave * 8 + srow) * 768 + ssl;

    for (int kt = 0; kt < 12; ++kt) {
        STG128(kt * 64)
        __syncthreads();
        #pragma unroll
        for (int h = 0; h < 2; ++h) {
            half8_t a[4], b[4];
            #pragma unroll
            for (int mi = 0; mi < 4; ++mi)
                a[mi] = *(const half8_t*)(As + (wm + mi * 16 + l15) * 64 +
                                          (((h * 4 + l4) ^ rs) << 3));
            #pragma unroll
            for (int ni = 0; ni < 4; ++ni)
                b[ni] = *(const half8_t*)(Bs + (wn + ni * 16 + l15) * 64 +
                                          (((h * 4 + l4) ^ rs) << 3));
            #pragma unroll
            for (int mi = 0; mi < 4; ++mi)
                #pragma unroll
                for (int ni = 0; ni < 4; ++ni)
                    acc[mi][ni] = MFMA16(a[mi], b[ni], acc[mi][ni]);
        }
        __syncthreads();
    }
}

// GEMM1: qkv = x @ w_qkv. Epilogue: q -> qh natural (relu); k -> khT (pos_enc+relu,
// half4 contiguous-n); v -> vhT (half4). Block cols all in one segment (768 = 6*128).
__global__ __launch_bounds__(256, 4) void gemm_qkv_kernel(
    const _Float16* __restrict__ xh, const _Float16* __restrict__ wqkvT,
    const float* __restrict__ pos_enc,
    _Float16* __restrict__ qh, _Float16* __restrict__ khT, _Float16* __restrict__ vhT) {
    __shared__ _Float16 As[8192];
    __shared__ _Float16 Bs[8192];
    int wgid = xcd_swizzle(blockIdx.x, 392 * 18);
    int mtile = wgid / 18, ntile = wgid - mtile * 18;
    f32x4 acc[4][4];
    run_gemm128(xh, wqkvT, mtile * 128, ntile * 128, As, Bs, acc);

    const int tid = threadIdx.x;
    const int lane = tid & 63;
    const int wave = tid >> 6;
    const int wm = (wave >> 1) * 64;
    const int wn = (wave & 1) * 64;
    const int l15 = lane & 15;
    const int l4 = lane >> 4;

    const int s = ntile / 6;
    const int cb = (ntile - s * 6) * 128 + wn;

    if (s == 0) {
        #pragma unroll
        for (int mi = 0; mi < 4; ++mi) {
            #pragma unroll
            for (int ni = 0; ni < 4; ++ni) {
                int c = cb + ni * 16 + l15;
                int h = c >> 6, d = c & 63;
                #pragma unroll
                for (int r = 0; r < 4; ++r) {
                    int gr = mtile * 128 + wm + mi * 16 + l4 * 4 + r;
                    int b = gr / 196;
                    int n = gr - b * 196;
                    qh[((size_t)(b * 12 + h) * 196 + n) * 64 + d] =
                        (_Float16)fmaxf(acc[mi][ni][r], 0.f);
                }
            }
        }
    } else {
        _Float16* dstT = (s == 1) ? khT : vhT;
        #pragma unroll
        for (int mi = 0; mi < 4; ++mi) {
            int gr0 = mtile * 128 + wm + mi * 16 + l4 * 4;
            int b = gr0 / 196, n0 = gr0 - b * 196;
            #pragma unroll
            for (int ni = 0; ni < 4; ++ni) {
                int c = cb + ni * 16 + l15;
                int h = c >> 6, d = c & 63;
                half4_t w;
                #pragma unroll
                for (int r = 0; r < 4; ++r) {
                    float v = acc[mi][ni][r];
                    if (s == 1) { v += pos_enc[(n0 + r) * 768 + c]; v = fmaxf(v, 0.f); }
                    w[r] = (_Float16)v;
                }
                *(half4_t*)(dstT + ((size_t)(b * 12 + h) * 64 + d) * 196 + n0) = w;
            }
        }
    }
}

// GEMM2: out = fused @ w_proj + b_proj (f32 out)
__global__ __launch_bounds__(256, 4) void gemm_proj_kernel(
    const _Float16* __restrict__ fused, const _Float16* __restrict__ wprojT,
    const float* __restrict__ b_proj, float* __restrict__ out) {
    __shared__ _Float16 As[8192];
    __shared__ _Float16 Bs[8192];
    int wgid = xcd_swizzle(blockIdx.x, 392 * 6);
    int mtile = wgid / 6, ntile = wgid - mtile * 6;
    f32x4 acc[4][4];
    run_gemm128(fused, wprojT, mtile * 128, ntile * 128, As, Bs, acc);

    const int tid = threadIdx.x;
    const int lane = tid & 63;
    const int wave = tid >> 6;
    const int wm = (wave >> 1) * 64;
    const int wn = (wave & 1) * 64;
    const int l15 = lane & 15;
    const int l4 = lane >> 4;

    #pragma unroll
    for (int mi = 0; mi < 4; ++mi) {
        #pragma unroll
        for (int ni = 0; ni < 4; ++ni) {
            int gc = ntile * 128 + wn + ni * 16 + l15;
            float bp = b_proj[gc];
            #pragma unroll
            for (int r = 0; r < 4; ++r) {
                int gr = mtile * 128 + wm + mi * 16 + l4 * 4 + r;
                out[(size_t)gr * 768 + gc] = acc[mi][ni][r] + bp;
            }
        }
    }
}

// ---------------- fused attention (R9-verified): no transpose, 2 blocks/CU ----------------
__global__ __launch_bounds__(512, 4) void attn_fused_kernel(
    const _Float16* __restrict__ qh, const _Float16* __restrict__ khT,
    const _Float16* __restrict__ vhT,
    const float* __restrict__ dwc_w, const float* __restrict__ dwc_b,
    _Float16* __restrict__ fused) {
    __shared__ _Float16 k_t[64 * 232];
    __shared__ _Float16 v_t[64 * 232];
    __shared__ _Float16 kv_l[64 * 64];
    __shared__ float ksum_p[512];
    __shared__ float ksum[64];
    __shared__ float zz[196];

    int bh = blockIdx.x;
    int bb = bh / 12, hh = bh - bb * 12;
    int tid = threadIdx.x;
    int lane = tid & 63, wave = tid >> 6;
    int l15 = lane & 15, l4 = lane >> 4;
    size_t base = (size_t)bh * 12544;

    // stage khT/vhT rows -> LDS [64][232] (rows 196 els + zero pad to 232)
    for (int s = tid; s < 1856; s += 512) {
        int c = s / 29, g = s - c * 29;
        half8_t kk = {0, 0, 0, 0, 0, 0, 0, 0}, vv = {0, 0, 0, 0, 0, 0, 0, 0};
        const _Float16* kp = khT + base + c * 196 + g * 8;
        const _Float16* vp = vhT + base + c * 196 + g * 8;
        if (g < 24) {
            kk = *(const half8_t*)kp; vv = *(const half8_t*)vp;
        } else if (g == 24) {
            half4_t k4 = *(const half4_t*)kp, v4 = *(const half4_t*)vp;
            kk[0] = k4[0]; kk[1] = k4[1]; kk[2] = k4[2]; kk[3] = k4[3];
            vv[0] = v4[0]; vv[1] = v4[1]; vv[2] = v4[2]; vv[3] = v4[3];
        }
        *(half8_t*)(k_t + c * 232 + g * 8) = kk;
        *(half8_t*)(v_t + c * 232 + g * 8) = vv;
    }
    __syncthreads();

    // kv = k^T v (64x64): wave -> (ct, dt0), (ct, dt0+1); store kv_l[d][c] swizzled
    {
        int ct = wave >> 1, dt0 = (wave & 1) * 2;
        f32x4 acc0 = {0.f, 0.f, 0.f, 0.f}, acc1 = {0.f, 0.f, 0.f, 0.f};
        #pragma unroll
        for (int ks = 0; ks < 7; ++ks) {
            half8_t a  = *(const half8_t*)(k_t + (ct * 16 + l15) * 232 + ks * 32 + l4 * 8);
            half8_t b0 = *(const half8_t*)(v_t + (dt0 * 16 + l15) * 232 + ks * 32 + l4 * 8);
            half8_t b1 = *(const half8_t*)(v_t + (dt0 * 16 + 16 + l15) * 232 + ks * 32 + l4 * 8);
            acc0 = MFMA16(a, b0, acc0);
            acc1 = MFMA16(a, b1, acc1);
        }
        half4_t h0, h1;
        #pragma unroll
        for (int r = 0; r < 4; ++r) { h0[r] = (_Float16)acc0[r]; h1[r] = (_Float16)acc1[r]; }
        int slot = ct * 2 + (l4 >> 1), sub = (l4 & 1) * 4;
        int d0 = dt0 * 16 + l15, d1 = d0 + 16;
        *(half4_t*)(kv_l + d0 * 64 + (((slot ^ (d0 & 7)) << 3) + sub)) = h0;
        *(half4_t*)(kv_l + d1 * 64 + (((slot ^ (d1 & 7)) << 3) + sub)) = h1;
    }
    // ksum partials
    {
        int n0 = wave * 25;
        int n1 = (n0 + 25 < 196) ? (n0 + 25) : 196;
        float s = 0.f;
        for (int n = n0; n < n1; ++n) s += (float)k_t[lane * 232 + n];
        ksum_p[wave * 64 + lane] = s;
    }
    __syncthreads();
    if (tid < 64) {
        float s = 0.f;
        #pragma unroll
        for (int w = 0; w < 8; ++w) s += ksum_p[w * 64 + tid];
        ksum[tid] = s;
    }
    __syncthreads();
    if (tid < 196) {
        const _Float16* qrow = qh + base + tid * 64;
        float s = 0.f;
        #pragma unroll
        for (int c8 = 0; c8 < 8; ++c8) {
            half8_t qv = *(const half8_t*)(qrow + c8 * 8);
            #pragma unroll
            for (int j = 0; j < 8; ++j) s += (float)qv[j] * ksum[c8 * 8 + j];
        }
        zz[tid] = 1.0f / (s + 1e-6f);
    }
    __syncthreads();

    // PV + depthwise conv; q A-frags straight from global
    for (int t = wave; t < 52; t += 8) {
        int mt = t >> 2, dt = t & 3;
        int d = dt * 16 + l15;
        f32x4 acc = {0.f, 0.f, 0.f, 0.f};
        const _Float16* qrow = qh + base + (mt * 16 + l15) * 64;
        half8_t a0 = *(const half8_t*)(qrow + l4 * 8);
        half8_t a1 = *(const half8_t*)(qrow + 32 + l4 * 8);
        half8_t b0 = *(const half8_t*)(kv_l + d * 64 + ((l4 ^ (d & 7)) << 3));
        half8_t b1 = *(const half8_t*)(kv_l + d * 64 + (((l4 + 4) ^ (d & 7)) << 3));
        acc = MFMA16(a0, b0, acc);
        acc = MFMA16(a1, b1, acc);

        float bd = dwc_b[d];
        float wc[25];
        #pragma unroll
        for (int j2 = 0; j2 < 25; ++j2) wc[j2] = dwc_w[d * 25 + j2];

        #pragma unroll
        for (int r = 0; r < 4; ++r) {
            int i = mt * 16 + l4 * 4 + r;
            if (i < 196) {
                int y = i / 14, x2 = i - y * 14;
                float cacc = bd;
                #pragma unroll
                for (int ky = 0; ky < 5; ++ky) {
                    int yy = y + ky - 2;
                    bool oky = (unsigned)yy < 14u;
                    #pragma unroll
                    for (int kx = 0; kx < 5; ++kx) {
                        int xx = x2 + kx - 2;
                        if (oky && (unsigned)xx < 14u)
                            cacc += (float)v_t[d * 232 + (yy * 14 + xx)] * wc[ky * 5 + kx];
                    }
                }
                float res = acc[r] * zz[i] + cacc;
                fused[((size_t)bb * 196 + i) * 768 + hh * 64 + d] = (_Float16)res;
            }
        }
    }
}

// ---------------- launcher ----------------

extern "C" void kernel_launch(void* const* d_in, const int* in_sizes, int n_in,
                              void* d_out, int out_size, void* d_ws, size_t ws_size,
                              hipStream_t stream) {
    const float* x       = (const float*)d_in[0];
    const float* w_qkv   = (const float*)d_in[1];
    const float* pos_enc = (const float*)d_in[2];
    const float* dwc_w   = (const float*)d_in[3];
    const float* dwc_b   = (const float*)d_in[4];
    const float* w_proj  = (const float*)d_in[5];
    const float* b_proj  = (const float*)d_in[6];

    const size_t NEEDED = 340574208;
    if (ws_size < NEEDED) return;  // insufficient scratch; bail

    char* ws = (char*)d_ws;
    _Float16* xh     = (_Float16*)(ws + 0);          // 77,070,336 B (also 'fused' later)
    _Float16* fused  = xh;                           // safe: attn reads qh/khT/vhT only
    _Float16* wqkvT  = (_Float16*)(ws + 77070336);   // 3,538,944
    _Float16* wprojT = (_Float16*)(ws + 80609280);   // 1,179,648
    _Float16* qh     = (_Float16*)(ws + 81788928);   // 77,070,336  natural [bh][196][64]
    _Float16* khT    = (_Float16*)(ws + 158859264);  // 77,070,336  transposed [bh][64][196]
    _Float16* vhT    = (_Float16*)(ws + 235929600);  // 77,070,336  transposed [bh][64][196]

    cvt_f2h_kernel<<<4096, 256, 0, stream>>>(x, xh, 9633792);
    transpose768_kernel<<<(2304 * 768 + 255) / 256, 256, 0, stream>>>(w_qkv, wqkvT, 2304);
    transpose768_kernel<<<(768 * 768 + 255) / 256, 256, 0, stream>>>(w_proj, wprojT, 768);
    gemm_qkv_kernel<<<392 * 18, 256, 0, stream>>>(xh, wqkvT, pos_enc, qh, khT, vhT);
    attn_fused_kernel<<<3072, 512, 0, stream>>>(qh, khT, vhT, dwc_w, dwc_b, fused);
    gemm_proj_kernel<<<392 * 6, 256, 0, stream>>>(fused, wprojT, b_proj, (float*)d_out);
}

// Round 13
// 616.899 us; speedup vs baseline: 1.5221x; 1.0470x over previous
//
#include <hip/hip_runtime.h>

typedef _Float16 half8_t __attribute__((ext_vector_type(8)));
typedef _Float16 half4_t __attribute__((ext_vector_type(4)));
typedef float f32x4 __attribute__((ext_vector_type(4)));

#define MFMA16(a, b, c) __builtin_amdgcn_mfma_f32_16x16x32_f16((a), (b), (c), 0, 0, 0)

typedef const unsigned int __attribute__((address_space(1)))* gas_ptr;
typedef unsigned int __attribute__((address_space(3)))* las_ptr;

__device__ __forceinline__ void gload16(const void* g, void* l) {
    __builtin_amdgcn_global_load_lds((gas_ptr)g, (las_ptr)l, 16, 0, 0);
}

// m204 bijective XCD swizzle: contiguous wgid chunk per XCD
__device__ __forceinline__ int xcd_swizzle(int bid, int nwg) {
    int xcd = bid & 7, i = bid >> 3;
    int q = nwg >> 3, r = nwg & 7;
    return (xcd < r ? xcd * (q + 1) : r * (q + 1) + (xcd - r) * q) + i;
}

// ---------------- convert / transpose ----------------

__global__ void cvt_f2h_kernel(const float* __restrict__ in, _Float16* __restrict__ out, int n4) {
    int stride = gridDim.x * blockDim.x;
    for (int i = blockIdx.x * blockDim.x + threadIdx.x; i < n4; i += stride) {
        f32x4 v = *(const f32x4*)(in + (size_t)4 * i);
        half4_t h;
        h[0] = (_Float16)v[0]; h[1] = (_Float16)v[1];
        h[2] = (_Float16)v[2]; h[3] = (_Float16)v[3];
        *(half4_t*)(out + (size_t)4 * i) = h;
    }
}

// out[j][k] = in[k][j], K fixed at 768
__global__ void transpose768_kernel(const float* __restrict__ in, _Float16* __restrict__ out, int ncols) {
    int idx = blockIdx.x * 256 + threadIdx.x;
    int total = ncols * 768;
    if (idx < total) {
        int j = idx / 768;
        int k = idx - j * 768;
        out[idx] = (_Float16)in[(size_t)k * ncols + j];
    }
}

// ---------------- GEMM core: m97-class 128x128 tile, 4 waves, BK=64, single-buffer ----
// (R12-verified: 0 conflicts, 4 blocks/CU)

#define STG128(kof)                                                               \
    {                                                                             \
        _Pragma("unroll")                                                         \
        for (int i = 0; i < 4; ++i) {                                             \
            gload16(ArowS + (kof) + i * 24576, As + wave * 512 + i * 2048);       \
            gload16(BrowS + (kof) + i * 24576, Bs + wave * 512 + i * 2048);       \
        }                                                                         \
    }

__device__ __forceinline__ void run_gemm128(const _Float16* __restrict__ A,
                                            const _Float16* __restrict__ Bt,
                                            int mbase, int nbase,
                                            _Float16* As, _Float16* Bs,   // 8192 f16 each
                                            f32x4 (&acc)[4][4]) {
    const int tid = threadIdx.x;
    const int lane = tid & 63;
    const int wave = tid >> 6;
    const int wm = (wave >> 1) * 64;
    const int wn = (wave & 1) * 64;
    const int l15 = lane & 15;
    const int l4 = lane >> 4;
    const int rs = l15 & 7;                                   // read swizzle key
    const int srow = lane >> 3;                               // staging row-in-8 (0..7)
    const int ssl = ((lane & 7) ^ srow) << 3;                 // staging source slot offset

    #pragma unroll
    for (int mi = 0; mi < 4; ++mi)
        #pragma unroll
        for (int ni = 0; ni < 4; ++ni)
            acc[mi][ni] = (f32x4){0.f, 0.f, 0.f, 0.f};

    const _Float16* ArowS = A + (size_t)(mbase + wave * 8 + srow) * 768 + ssl;
    const _Float16* BrowS = Bt + (size_t)(nbase + wave * 8 + srow) * 768 + ssl;

    for (int kt = 0; kt < 12; ++kt) {
        STG128(kt * 64)
        __syncthreads();
        #pragma unroll
        for (int h = 0; h < 2; ++h) {
            half8_t a[4], b[4];
            #pragma unroll
            for (int mi = 0; mi < 4; ++mi)
                a[mi] = *(const half8_t*)(As + (wm + mi * 16 + l15) * 64 +
                                          (((h * 4 + l4) ^ rs) << 3));
            #pragma unroll
            for (int ni = 0; ni < 4; ++ni)
                b[ni] = *(const half8_t*)(Bs + (wn + ni * 16 + l15) * 64 +
                                          (((h * 4 + l4) ^ rs) << 3));
            #pragma unroll
            for (int mi = 0; mi < 4; ++mi)
                #pragma unroll
                for (int ni = 0; ni < 4; ++ni)
                    acc[mi][ni] = MFMA16(a[mi], b[ni], acc[mi][ni]);
        }
        __syncthreads();
    }
}

// GEMM1: qkv = x @ w_qkv. XCD half-N partition: XCDs 0-3 own ntiles 0-8,
// XCDs 4-7 own ntiles 9-17; each XCD a contiguous 98-mtile band. Per-XCD L2
// working set = streaming A (2.75 MB window) + resident B-half (1.77 MB) < 4 MiB
// -> B-thrash (R12: 420 MB fetch) eliminated; A fetched 2x (154 MB) instead.
__global__ __launch_bounds__(256, 4) void gemm_qkv_kernel(
    const _Float16* __restrict__ xh, const _Float16* __restrict__ wqkvT,
    const float* __restrict__ pos_enc,
    _Float16* __restrict__ qh, _Float16* __restrict__ khT, _Float16* __restrict__ vhT) {
    __shared__ _Float16 As[8192];
    __shared__ _Float16 Bs[8192];
    int bid = blockIdx.x;
    int xcd = bid & 7, i = bid >> 3;          // i in 0..881
    int xq = xcd & 3, nhalf = xcd >> 2;
    int mtl = i / 9, ntl = i - mtl * 9;       // mtl 0..97
    int mtile = xq * 98 + mtl;
    int ntile = nhalf * 9 + ntl;
    f32x4 acc[4][4];
    run_gemm128(xh, wqkvT, mtile * 128, ntile * 128, As, Bs, acc);

    const int tid = threadIdx.x;
    const int lane = tid & 63;
    const int wave = tid >> 6;
    const int wm = (wave >> 1) * 64;
    const int wn = (wave & 1) * 64;
    const int l15 = lane & 15;
    const int l4 = lane >> 4;

    const int s = ntile / 6;
    const int cb = (ntile - s * 6) * 128 + wn;

    if (s == 0) {
        #pragma unroll
        for (int mi = 0; mi < 4; ++mi) {
            #pragma unroll
            for (int ni = 0; ni < 4; ++ni) {
                int c = cb + ni * 16 + l15;
                int h = c >> 6, d = c & 63;
                #pragma unroll
                for (int r = 0; r < 4; ++r) {
                    int gr = mtile * 128 + wm + mi * 16 + l4 * 4 + r;
                    int b = gr / 196;
                    int n = gr - b * 196;
                    qh[((size_t)(b * 12 + h) * 196 + n) * 64 + d] =
                        (_Float16)fmaxf(acc[mi][ni][r], 0.f);
                }
            }
        }
    } else {
        _Float16* dstT = (s == 1) ? khT : vhT;
        #pragma unroll
        for (int mi = 0; mi < 4; ++mi) {
            int gr0 = mtile * 128 + wm + mi * 16 + l4 * 4;
            int b = gr0 / 196, n0 = gr0 - b * 196;
            #pragma unroll
            for (int ni = 0; ni < 4; ++ni) {
                int c = cb + ni * 16 + l15;
                int h = c >> 6, d = c & 63;
                half4_t w;
                #pragma unroll
                for (int r = 0; r < 4; ++r) {
                    float v = acc[mi][ni][r];
                    if (s == 1) { v += pos_enc[(n0 + r) * 768 + c]; v = fmaxf(v, 0.f); }
                    w[r] = (_Float16)v;
                }
                *(half4_t*)(dstT + ((size_t)(b * 12 + h) * 64 + d) * 196 + n0) = w;
            }
        }
    }
}

// GEMM2: out = fused @ w_proj + b_proj (f32 out); B=1.18 MB fits L2 everywhere
__global__ __launch_bounds__(256, 4) void gemm_proj_kernel(
    const _Float16* __restrict__ fused, const _Float16* __restrict__ wprojT,
    const float* __restrict__ b_proj, float* __restrict__ out) {
    __shared__ _Float16 As[8192];
    __shared__ _Float16 Bs[8192];
    int wgid = xcd_swizzle(blockIdx.x, 392 * 6);
    int mtile = wgid / 6, ntile = wgid - mtile * 6;
    f32x4 acc[4][4];
    run_gemm128(fused, wprojT, mtile * 128, ntile * 128, As, Bs, acc);

    const int tid = threadIdx.x;
    const int lane = tid & 63;
    const int wave = tid >> 6;
    const int wm = (wave >> 1) * 64;
    const int wn = (wave & 1) * 64;
    const int l15 = lane & 15;
    const int l4 = lane >> 4;

    #pragma unroll
    for (int mi = 0; mi < 4; ++mi) {
        #pragma unroll
        for (int ni = 0; ni < 4; ++ni) {
            int gc = ntile * 128 + wn + ni * 16 + l15;
            float bp = b_proj[gc];
            #pragma unroll
            for (int r = 0; r < 4; ++r) {
                int gr = mtile * 128 + wm + mi * 16 + l4 * 4 + r;
                out[(size_t)gr * 768 + gc] = acc[mi][ni][r] + bp;
            }
        }
    }
}

// ---------------- fused attention (R9-verified): no transpose, 2 blocks/CU ----------------
__global__ __launch_bounds__(512, 4) void attn_fused_kernel(
    const _Float16* __restrict__ qh, const _Float16* __restrict__ khT,
    const _Float16* __restrict__ vhT,
    const float* __restrict__ dwc_w, const float* __restrict__ dwc_b,
    _Float16* __restrict__ fused) {
    __shared__ _Float16 k_t[64 * 232];
    __shared__ _Float16 v_t[64 * 232];
    __shared__ _Float16 kv_l[64 * 64];
    __shared__ float ksum_p[512];
    __shared__ float ksum[64];
    __shared__ float zz[196];

    int bh = blockIdx.x;
    int bb = bh / 12, hh = bh - bb * 12;
    int tid = threadIdx.x;
    int lane = tid & 63, wave = tid >> 6;
    int l15 = lane & 15, l4 = lane >> 4;
    size_t base = (size_t)bh * 12544;

    // stage khT/vhT rows -> LDS [64][232] (rows 196 els + zero pad to 232)
    for (int s = tid; s < 1856; s += 512) {
        int c = s / 29, g = s - c * 29;
        half8_t kk = {0, 0, 0, 0, 0, 0, 0, 0}, vv = {0, 0, 0, 0, 0, 0, 0, 0};
        const _Float16* kp = khT + base + c * 196 + g * 8;
        const _Float16* vp = vhT + base + c * 196 + g * 8;
        if (g < 24) {
            kk = *(const half8_t*)kp; vv = *(const half8_t*)vp;
        } else if (g == 24) {
            half4_t k4 = *(const half4_t*)kp, v4 = *(const half4_t*)vp;
            kk[0] = k4[0]; kk[1] = k4[1]; kk[2] = k4[2]; kk[3] = k4[3];
            vv[0] = v4[0]; vv[1] = v4[1]; vv[2] = v4[2]; vv[3] = v4[3];
        }
        *(half8_t*)(k_t + c * 232 + g * 8) = kk;
        *(half8_t*)(v_t + c * 232 + g * 8) = vv;
    }
    __syncthreads();

    // kv = k^T v (64x64): wave -> (ct, dt0), (ct, dt0+1); store kv_l[d][c] swizzled
    {
        int ct = wave >> 1, dt0 = (wave & 1) * 2;
        f32x4 acc0 = {0.f, 0.f, 0.f, 0.f}, acc1 = {0.f, 0.f, 0.f, 0.f};
        #pragma unroll
        for (int ks = 0; ks < 7; ++ks) {
            half8_t a  = *(const half8_t*)(k_t + (ct * 16 + l15) * 232 + ks * 32 + l4 * 8);
            half8_t b0 = *(const half8_t*)(v_t + (dt0 * 16 + l15) * 232 + ks * 32 + l4 * 8);
            half8_t b1 = *(const half8_t*)(v_t + (dt0 * 16 + 16 + l15) * 232 + ks * 32 + l4 * 8);
            acc0 = MFMA16(a, b0, acc0);
            acc1 = MFMA16(a, b1, acc1);
        }
        half4_t h0, h1;
        #pragma unroll
        for (int r = 0; r < 4; ++r) { h0[r] = (_Float16)acc0[r]; h1[r] = (_Float16)acc1[r]; }
        int slot = ct * 2 + (l4 >> 1), sub = (l4 & 1) * 4;
        int d0 = dt0 * 16 + l15, d1 = d0 + 16;
        *(half4_t*)(kv_l + d0 * 64 + (((slot ^ (d0 & 7)) << 3) + sub)) = h0;
        *(half4_t*)(kv_l + d1 * 64 + (((slot ^ (d1 & 7)) << 3) + sub)) = h1;
    }
    // ksum partials
    {
        int n0 = wave * 25;
        int n1 = (n0 + 25 < 196) ? (n0 + 25) : 196;
        float s = 0.f;
        for (int n = n0; n < n1; ++n) s += (float)k_t[lane * 232 + n];
        ksum_p[wave * 64 + lane] = s;
    }
    __syncthreads();
    if (tid < 64) {
        float s = 0.f;
        #pragma unroll
        for (int w = 0; w < 8; ++w) s += ksum_p[w * 64 + tid];
        ksum[tid] = s;
    }
    __syncthreads();
    if (tid < 196) {
        const _Float16* qrow = qh + base + tid * 64;
        float s = 0.f;
        #pragma unroll
        for (int c8 = 0; c8 < 8; ++c8) {
            half8_t qv = *(const half8_t*)(qrow + c8 * 8);
            #pragma unroll
            for (int j = 0; j < 8; ++j) s += (float)qv[j] * ksum[c8 * 8 + j];
        }
        zz[tid] = 1.0f / (s + 1e-6f);
    }
    __syncthreads();

    // PV + depthwise conv; q A-frags straight from global
    for (int t = wave; t < 52; t += 8) {
        int mt = t >> 2, dt = t & 3;
        int d = dt * 16 + l15;
        f32x4 acc = {0.f, 0.f, 0.f, 0.f};
        const _Float16* qrow = qh + base + (mt * 16 + l15) * 64;
        half8_t a0 = *(const half8_t*)(qrow + l4 * 8);
        half8_t a1 = *(const half8_t*)(qrow + 32 + l4 * 8);
        half8_t b0 = *(const half8_t*)(kv_l + d * 64 + ((l4 ^ (d & 7)) << 3));
        half8_t b1 = *(const half8_t*)(kv_l + d * 64 + (((l4 + 4) ^ (d & 7)) << 3));
        acc = MFMA16(a0, b0, acc);
        acc = MFMA16(a1, b1, acc);

        float bd = dwc_b[d];
        float wc[25];
        #pragma unroll
        for (int j2 = 0; j2 < 25; ++j2) wc[j2] = dwc_w[d * 25 + j2];

        #pragma unroll
        for (int r = 0; r < 4; ++r) {
            int i = mt * 16 + l4 * 4 + r;
            if (i < 196) {
                int y = i / 14, x2 = i - y * 14;
                float cacc = bd;
                #pragma unroll
                for (int ky = 0; ky < 5; ++ky) {
                    int yy = y + ky - 2;
                    bool oky = (unsigned)yy < 14u;
                    #pragma unroll
                    for (int kx = 0; kx < 5; ++kx) {
                        int xx = x2 + kx - 2;
                        if (oky && (unsigned)xx < 14u)
                            cacc += (float)v_t[d * 232 + (yy * 14 + xx)] * wc[ky * 5 + kx];
                    }
                }
                float res = acc[r] * zz[i] + cacc;
                fused[((size_t)bb * 196 + i) * 768 + hh * 64 + d] = (_Float16)res;
            }
        }
    }
}

// ---------------- launcher ----------------

extern "C" void kernel_launch(void* const* d_in, const int* in_sizes, int n_in,
                              void* d_out, int out_size, void* d_ws, size_t ws_size,
                              hipStream_t stream) {
    const float* x       = (const float*)d_in[0];
    const float* w_qkv   = (const float*)d_in[1];
    const float* pos_enc = (const float*)d_in[2];
    const float* dwc_w   = (const float*)d_in[3];
    const float* dwc_b   = (const float*)d_in[4];
    const float* w_proj  = (const float*)d_in[5];
    const float* b_proj  = (const float*)d_in[6];

    const size_t NEEDED = 340574208;
    if (ws_size < NEEDED) return;  // insufficient scratch; bail

    char* ws = (char*)d_ws;
    _Float16* xh     = (_Float16*)(ws + 0);          // 77,070,336 B (also 'fused' later)
    _Float16* fused  = xh;                           // safe: attn reads qh/khT/vhT only
    _Float16* wqkvT  = (_Float16*)(ws + 77070336);   // 3,538,944
    _Float16* wprojT = (_Float16*)(ws + 80609280);   // 1,179,648
    _Float16* qh     = (_Float16*)(ws + 81788928);   // 77,070,336  natural [bh][196][64]
    _Float16* khT    = (_Float16*)(ws + 158859264);  // 77,070,336  transposed [bh][64][196]
    _Float16* vhT    = (_Float16*)(ws + 235929600);  // 77,070,336  transposed [bh][64][196]

    cvt_f2h_kernel<<<4096, 256, 0, stream>>>(x, xh, 9633792);
    transpose768_kernel<<<(2304 * 768 + 255) / 256, 256, 0, stream>>>(w_qkv, wqkvT, 2304);
    transpose768_kernel<<<(768 * 768 + 255) / 256, 256, 0, stream>>>(w_proj, wprojT, 768);
    gemm_qkv_kernel<<<392 * 18, 256, 0, stream>>>(xh, wqkvT, pos_enc, qh, khT, vhT);
    attn_fused_kernel<<<3072, 512, 0, stream>>>(qh, khT, vhT, dwc_w, dwc_b, fused);
    gemm_proj_kernel<<<392 * 6, 256, 0, stream>>>(fused, wprojT, b_proj, (float*)d_out);
}

// Round 14
// 580.243 us; speedup vs baseline: 1.6182x; 1.0632x over previous
//
#include <hip/hip_runtime.h>

typedef _Float16 half8_t __attribute__((ext_vector_type(8)));
typedef _Float16 half4_t __attribute__((ext_vector_type(4)));
typedef _Float16 half2_t __attribute__((ext_vector_type(2)));
typedef float f32x4 __attribute__((ext_vector_type(4)));

#define MFMA16(a, b, c) __builtin_amdgcn_mfma_f32_16x16x32_f16((a), (b), (c), 0, 0, 0)

typedef const unsigned int __attribute__((address_space(1)))* gas_ptr;
typedef unsigned int __attribute__((address_space(3)))* las_ptr;

__device__ __forceinline__ void gload16(const void* g, void* l) {
    __builtin_amdgcn_global_load_lds((gas_ptr)g, (las_ptr)l, 16, 0, 0);
}

// m204 bijective XCD swizzle: contiguous wgid chunk per XCD
__device__ __forceinline__ int xcd_swizzle(int bid, int nwg) {
    int xcd = bid & 7, i = bid >> 3;
    int q = nwg >> 3, r = nwg & 7;
    return (xcd < r ? xcd * (q + 1) : r * (q + 1) + (xcd - r) * q) + i;
}

// ---------------- convert / transpose ----------------

__global__ void cvt_f2h_kernel(const float* __restrict__ in, _Float16* __restrict__ out, int n4) {
    int stride = gridDim.x * blockDim.x;
    for (int i = blockIdx.x * blockDim.x + threadIdx.x; i < n4; i += stride) {
        f32x4 v = *(const f32x4*)(in + (size_t)4 * i);
        half4_t h;
        h[0] = (_Float16)v[0]; h[1] = (_Float16)v[1];
        h[2] = (_Float16)v[2]; h[3] = (_Float16)v[3];
        *(half4_t*)(out + (size_t)4 * i) = h;
    }
}

// out[j][k] = in[k][j], K fixed at 768
__global__ void transpose768_kernel(const float* __restrict__ in, _Float16* __restrict__ out, int ncols) {
    int idx = blockIdx.x * 256 + threadIdx.x;
    int total = ncols * 768;
    if (idx < total) {
        int j = idx / 768;
        int k = idx - j * 768;
        out[idx] = (_Float16)in[(size_t)k * ncols + j];
    }
}

// ---------------- GEMM core: m97-class 128x128 tile, 4 waves, BK=64, single-buffer ----
// (R12/R13-verified: 0 conflicts, 4 blocks/CU)

#define STG128(kof)                                                               \
    {                                                                             \
        _Pragma("unroll")                                                         \
        for (int i = 0; i < 4; ++i) {                                             \
            gload16(ArowS + (kof) + i * 24576, As + wave * 512 + i * 2048);       \
            gload16(BrowS + (kof) + i * 24576, Bs + wave * 512 + i * 2048);       \
        }                                                                         \
    }

__device__ __forceinline__ void run_gemm128(const _Float16* __restrict__ A,
                                            const _Float16* __restrict__ Bt,
                                            int mbase, int nbase,
                                            _Float16* As, _Float16* Bs,   // 8192 f16 each
                                            f32x4 (&acc)[4][4]) {
    const int tid = threadIdx.x;
    const int lane = tid & 63;
    const int wave = tid >> 6;
    const int wm = (wave >> 1) * 64;
    const int wn = (wave & 1) * 64;
    const int l15 = lane & 15;
    const int l4 = lane >> 4;
    const int rs = l15 & 7;                                   // read swizzle key
    const int srow = lane >> 3;                               // staging row-in-8 (0..7)
    const int ssl = ((lane & 7) ^ srow) << 3;                 // staging source slot offset

    #pragma unroll
    for (int mi = 0; mi < 4; ++mi)
        #pragma unroll
        for (int ni = 0; ni < 4; ++ni)
            acc[mi][ni] = (f32x4){0.f, 0.f, 0.f, 0.f};

    const _Float16* ArowS = A + (size_t)(mbase + wave * 8 + srow) * 768 + ssl;
    const _Float16* BrowS = Bt + (size_t)(nbase + wave * 8 + srow) * 768 + ssl;

    for (int kt = 0; kt < 12; ++kt) {
        STG128(kt * 64)
        __syncthreads();
        #pragma unroll
        for (int h = 0; h < 2; ++h) {
            half8_t a[4], b[4];
            #pragma unroll
            for (int mi = 0; mi < 4; ++mi)
                a[mi] = *(const half8_t*)(As + (wm + mi * 16 + l15) * 64 +
                                          (((h * 4 + l4) ^ rs) << 3));
            #pragma unroll
            for (int ni = 0; ni < 4; ++ni)
                b[ni] = *(const half8_t*)(Bs + (wn + ni * 16 + l15) * 64 +
                                          (((h * 4 + l4) ^ rs) << 3));
            #pragma unroll
            for (int mi = 0; mi < 4; ++mi)
                #pragma unroll
                for (int ni = 0; ni < 4; ++ni)
                    acc[mi][ni] = MFMA16(a[mi], b[ni], acc[mi][ni]);
        }
        __syncthreads();
    }
}

// GEMM1: qkv = x @ w_qkv. q -> qh natural [bh][196][64] (relu);
// k/v -> khT/vhT [bh][64][224] (stride 224, 16B-aligned rows; pads 196..223 zeroed
// by the n0==192 thread so attn's K=224 MFMA tiling reads zeros).
__global__ __launch_bounds__(256, 4) void gemm_qkv_kernel(
    const _Float16* __restrict__ xh, const _Float16* __restrict__ wqkvT,
    const float* __restrict__ pos_enc,
    _Float16* __restrict__ qh, _Float16* __restrict__ khT, _Float16* __restrict__ vhT) {
    __shared__ _Float16 As[8192];
    __shared__ _Float16 Bs[8192];
    int bid = blockIdx.x;
    int xcd = bid & 7, i = bid >> 3;          // L2 half-N partition (R13-verified)
    int xq = xcd & 3, nhalf = xcd >> 2;
    int mtl = i / 9, ntl = i - mtl * 9;
    int mtile = xq * 98 + mtl;
    int ntile = nhalf * 9 + ntl;
    f32x4 acc[4][4];
    run_gemm128(xh, wqkvT, mtile * 128, ntile * 128, As, Bs, acc);

    const int tid = threadIdx.x;
    const int lane = tid & 63;
    const int wave = tid >> 6;
    const int wm = (wave >> 1) * 64;
    const int wn = (wave & 1) * 64;
    const int l15 = lane & 15;
    const int l4 = lane >> 4;

    const int s = ntile / 6;
    const int cb = (ntile - s * 6) * 128 + wn;

    if (s == 0) {
        #pragma unroll
        for (int mi = 0; mi < 4; ++mi) {
            #pragma unroll
            for (int ni = 0; ni < 4; ++ni) {
                int c = cb + ni * 16 + l15;
                int h = c >> 6, d = c & 63;
                #pragma unroll
                for (int r = 0; r < 4; ++r) {
                    int gr = mtile * 128 + wm + mi * 16 + l4 * 4 + r;
                    int b = gr / 196;
                    int n = gr - b * 196;
                    qh[((size_t)(b * 12 + h) * 196 + n) * 64 + d] =
                        (_Float16)fmaxf(acc[mi][ni][r], 0.f);
                }
            }
        }
    } else {
        _Float16* dstT = (s == 1) ? khT : vhT;
        #pragma unroll
        for (int mi = 0; mi < 4; ++mi) {
            int gr0 = mtile * 128 + wm + mi * 16 + l4 * 4;
            int b = gr0 / 196, n0 = gr0 - b * 196;
            #pragma unroll
            for (int ni = 0; ni < 4; ++ni) {
                int c = cb + ni * 16 + l15;
                int h = c >> 6, d = c & 63;
                _Float16* row = dstT + ((size_t)(b * 12 + h) * 64 + d) * 224;
                half4_t w;
                #pragma unroll
                for (int r = 0; r < 4; ++r) {
                    float v = acc[mi][ni][r];
                    if (s == 1) { v += pos_enc[(n0 + r) * 768 + c]; v = fmaxf(v, 0.f); }
                    w[r] = (_Float16)v;
                }
                *(half4_t*)(row + n0) = w;
                if (n0 == 192) {
                    half4_t z4 = {(_Float16)0.f, (_Float16)0.f, (_Float16)0.f, (_Float16)0.f};
                    #pragma unroll
                    for (int p = 196; p < 224; p += 4) *(half4_t*)(row + p) = z4;
                }
            }
        }
    }
}

// GEMM2: out = fused @ w_proj + b_proj (f32 out)
__global__ __launch_bounds__(256, 4) void gemm_proj_kernel(
    const _Float16* __restrict__ fused, const _Float16* __restrict__ wprojT,
    const float* __restrict__ b_proj, float* __restrict__ out) {
    __shared__ _Float16 As[8192];
    __shared__ _Float16 Bs[8192];
    int wgid = xcd_swizzle(blockIdx.x, 392 * 6);
    int mtile = wgid / 6, ntile = wgid - mtile * 6;
    f32x4 acc[4][4];
    run_gemm128(fused, wprojT, mtile * 128, ntile * 128, As, Bs, acc);

    const int tid = threadIdx.x;
    const int lane = tid & 63;
    const int wave = tid >> 6;
    const int wm = (wave >> 1) * 64;
    const int wn = (wave & 1) * 64;
    const int l15 = lane & 15;
    const int l4 = lane >> 4;

    #pragma unroll
    for (int mi = 0; mi < 4; ++mi) {
        #pragma unroll
        for (int ni = 0; ni < 4; ++ni) {
            int gc = ntile * 128 + wn + ni * 16 + l15;
            float bp = b_proj[gc];
            #pragma unroll
            for (int r = 0; r < 4; ++r) {
                int gr = mtile * 128 + wm + mi * 16 + l4 * 4 + r;
                out[(size_t)gr * 768 + gc] = acc[mi][ni][r] + bp;
            }
        }
    }
}

// ---------------- fused attention v3: no LDS staging, global-frag MFMA, 3 blocks/CU ----
// khT/vhT: [bh][64][224] (pads zeroed). LDS = kv_l 8K + pv 30K + ksum/zz ~1K = 39.5 KB.
// Phases: {ksum(shfl), kv(global frags)} -> bar -> {z} -> bar -> {PV -> pv LDS} -> bar
//         -> {conv from global v rows + pv + write fused (d-contiguous, coalesced)}.
__global__ __launch_bounds__(512, 6) void attn_fused_kernel(
    const _Float16* __restrict__ qh, const _Float16* __restrict__ khT,
    const _Float16* __restrict__ vhT,
    const float* __restrict__ dwc_w, const float* __restrict__ dwc_b,
    _Float16* __restrict__ fused) {
    __shared__ _Float16 kv_l[64 * 64];
    __shared__ _Float16 pv[64 * 236];
    __shared__ float ksum[64];
    __shared__ float zz[196];

    int bh = blockIdx.x;
    int bb = bh / 12, hh = bh - bb * 12;
    int tid = threadIdx.x;
    int lane = tid & 63, wave = tid >> 6;
    int l15 = lane & 15, l4 = lane >> 4;
    size_t kbase = (size_t)bh * 14336;   // 64*224
    size_t qbase = (size_t)bh * 12544;

    // ---- ksum: wave w owns channels c = w*8..w*8+7; contiguous half4 + shfl reduce ----
    #pragma unroll
    for (int j = 0; j < 8; ++j) {
        int c = wave * 8 + j;
        float s = 0.f;
        if (lane < 49) {
            half4_t kq = *(const half4_t*)(khT + kbase + c * 224 + lane * 4);
            s = (float)kq[0] + (float)kq[1] + (float)kq[2] + (float)kq[3];
        }
        #pragma unroll
        for (int off = 32; off; off >>= 1) s += __shfl_down(s, off);
        if (lane == 0) ksum[c] = s;
    }

    // ---- kv = k^T v (64x64), frags from global; store kv_l swizzled (R13 layout) ----
    {
        int ct = wave >> 1, dt0 = (wave & 1) * 2;
        const _Float16* ka  = khT + kbase + (ct * 16 + l15) * 224 + l4 * 8;
        const _Float16* vb0 = vhT + kbase + (dt0 * 16 + l15) * 224 + l4 * 8;
        const _Float16* vb1 = vb0 + 16 * 224;
        f32x4 acc0 = {0.f, 0.f, 0.f, 0.f}, acc1 = {0.f, 0.f, 0.f, 0.f};
        #pragma unroll
        for (int ks = 0; ks < 7; ++ks) {
            half8_t a  = *(const half8_t*)(ka + ks * 32);
            half8_t b0 = *(const half8_t*)(vb0 + ks * 32);
            half8_t b1 = *(const half8_t*)(vb1 + ks * 32);
            acc0 = MFMA16(a, b0, acc0);
            acc1 = MFMA16(a, b1, acc1);
        }
        half4_t h0, h1;
        #pragma unroll
        for (int r = 0; r < 4; ++r) { h0[r] = (_Float16)acc0[r]; h1[r] = (_Float16)acc1[r]; }
        int slot = ct * 2 + (l4 >> 1), sub = (l4 & 1) * 4;
        int d0 = dt0 * 16 + l15, d1 = d0 + 16;
        *(half4_t*)(kv_l + d0 * 64 + (((slot ^ (d0 & 7)) << 3) + sub)) = h0;
        *(half4_t*)(kv_l + d1 * 64 + (((slot ^ (d1 & 7)) << 3) + sub)) = h1;
    }
    __syncthreads();

    // ---- z ----
    if (tid < 196) {
        const _Float16* qrow = qh + qbase + tid * 64;
        float s = 0.f;
        #pragma unroll
        for (int c8 = 0; c8 < 8; ++c8) {
            half8_t qv = *(const half8_t*)(qrow + c8 * 8);
            #pragma unroll
            for (int j = 0; j < 8; ++j) s += (float)qv[j] * ksum[c8 * 8 + j];
        }
        zz[tid] = 1.0f / (s + 1e-6f);
    }
    __syncthreads();

    // ---- PV: pv[d][i] = zz[i] * (q @ kv), half4 writes ----
    for (int t = wave; t < 52; t += 8) {
        int mt = t >> 2, dt = t & 3;
        int d = dt * 16 + l15;
        f32x4 acc = {0.f, 0.f, 0.f, 0.f};
        const _Float16* qrow = qh + qbase + (mt * 16 + l15) * 64;
        half8_t a0 = *(const half8_t*)(qrow + l4 * 8);
        half8_t a1 = *(const half8_t*)(qrow + 32 + l4 * 8);
        half8_t b0 = *(const half8_t*)(kv_l + d * 64 + ((l4 ^ (d & 7)) << 3));
        half8_t b1 = *(const half8_t*)(kv_l + d * 64 + (((l4 + 4) ^ (d & 7)) << 3));
        acc = MFMA16(a0, b0, acc);
        acc = MFMA16(a1, b1, acc);
        int i0 = mt * 16 + l4 * 4;
        half4_t w;
        #pragma unroll
        for (int r = 0; r < 4; ++r) {
            int i = i0 + r;
            w[r] = (_Float16)(acc[r] * ((i < 196) ? zz[i] : 0.f));
        }
        *(half4_t*)(pv + d * 236 + i0) = w;
    }
    __syncthreads();

    // ---- conv (from global v rows) + combine pv + write fused ----
    #pragma unroll
    for (int rnd = 0; rnd < 2; ++rnd) {
        int y = rnd * 8 + wave;
        int d = lane;
        if (y < 14) {
            float cacc[14];
            float bd = dwc_b[d];
            #pragma unroll
            for (int x = 0; x < 14; ++x) cacc[x] = bd;
            const float* wrow = dwc_w + d * 25;
            #pragma unroll
            for (int ky = 0; ky < 5; ++ky) {
                int yy = y + ky - 2;
                if ((unsigned)yy < 14u) {
                    const _Float16* vr = vhT + kbase + d * 224 + yy * 14;
                    float hv[14];
                    #pragma unroll
                    for (int u = 0; u < 7; ++u) {
                        half2_t w2 = *(const half2_t*)(vr + u * 2);
                        hv[2 * u] = (float)w2[0];
                        hv[2 * u + 1] = (float)w2[1];
                    }
                    #pragma unroll
                    for (int kx = 0; kx < 5; ++kx) {
                        float wk = wrow[ky * 5 + kx];
                        #pragma unroll
                        for (int x = 0; x < 14; ++x) {
                            int c = x + kx - 2;          // compile-time per (x,kx)
                            if (c >= 0 && c < 14) cacc[x] += hv[c] * wk;
                        }
                    }
                }
            }
            int ibase = y * 14;
            _Float16* orow = fused + ((size_t)bb * 196 + ibase) * 768 + hh * 64 + d;
            #pragma unroll
            for (int xp = 0; xp < 7; ++xp) {
                half2_t pw = *(const half2_t*)(pv + d * 236 + ibase + 2 * xp);
                orow[(2 * xp) * 768]     = (_Float16)((float)pw[0] + cacc[2 * xp]);
                orow[(2 * xp + 1) * 768] = (_Float16)((float)pw[1] + cacc[2 * xp + 1]);
            }
        }
    }
}

// ---------------- launcher ----------------

extern "C" void kernel_launch(void* const* d_in, const int* in_sizes, int n_in,
                              void* d_out, int out_size, void* d_ws, size_t ws_size,
                              hipStream_t stream) {
    const float* x       = (const float*)d_in[0];
    const float* w_qkv   = (const float*)d_in[1];
    const float* pos_enc = (const float*)d_in[2];
    const float* dwc_w   = (const float*)d_in[3];
    const float* dwc_b   = (const float*)d_in[4];
    const float* w_proj  = (const float*)d_in[5];
    const float* b_proj  = (const float*)d_in[6];

    const size_t NEEDED = 340574208;
    if (ws_size < NEEDED) return;  // insufficient scratch; bail

    char* ws = (char*)d_ws;
    _Float16* xh     = (_Float16*)(ws + 0);          // 77,070,336 B (also 'fused' later)
    _Float16* fused  = xh;                           // safe: attn reads qh/khT/vhT only
    _Float16* wqkvT  = (_Float16*)(ws + 77070336);   // 3,538,944
    _Float16* wprojT = (_Float16*)(ws + 80609280);   // 1,179,648
    _Float16* qh     = (_Float16*)(ws + 81788928);   // 77,070,336  natural [bh][196][64]
    _Float16* khT    = (_Float16*)(ws + 158859264);  // 88,080,384  [bh][64][224]
    _Float16* vhT    = (_Float16*)(ws + 246939648);  // 88,080,384  [bh][64][224]
                                                     // end 335,020,032 <= NEEDED

    cvt_f2h_kernel<<<4096, 256, 0, stream>>>(x, xh, 9633792);
    transpose768_kernel<<<(2304 * 768 + 255) / 256, 256, 0, stream>>>(w_qkv, wqkvT, 2304);
    transpose768_kernel<<<(768 * 768 + 255) / 256, 256, 0, stream>>>(w_proj, wprojT, 768);
    gemm_qkv_kernel<<<392 * 18, 256, 0, stream>>>(xh, wqkvT, pos_enc, qh, khT, vhT);
    attn_fused_kernel<<<3072, 512, 0, stream>>>(qh, khT, vhT, dwc_w, dwc_b, fused);
    gemm_proj_kernel<<<392 * 6, 256, 0, stream>>>(fused, wprojT, b_proj, (float*)d_out);
}